// Round 6
// baseline (1109.287 us; speedup 1.0000x reference)
//
#include <hip/hip_runtime.h>
#include <math.h>

#define N_NODES 100000
#define N_EDGES 1600000
#define IN_FEAT 16
#define OUT_FEAT 16
#define HEADS 6
#define HF 96                 // HEADS*OUT_FEAT

// Bucketed-aggregate geometry:
#define NB 4096               // buckets
#define NPB 25                // nodes per bucket (4096*25 = 102400 >= 100000)
#define CAP 544               // per-bucket edge capacity. dst~Binom(1.6M,1/4096):
                              // mean 390.6, sigma 19.8 -> 544 is +7.8 sigma (never hit)
#define NBLK_PART 128         // partition blocks
#define DLS 100               // LDS 'num' stride per local node (100%32=4 -> bank spread)

// ---------------------------------------------------------------------------
// K1: attention logits a_src/a_dst per (node, head). x is NOT materialized;
// the aggregate kernel recomputes it from the 64B data row (R5 lesson: cheaper
// than gathering a >L2-sized x array).
// ---------------------------------------------------------------------------
__global__ void node_transform(const float* __restrict__ data,
                               const float* __restrict__ W,
                               const float* __restrict__ att_src,
                               const float* __restrict__ att_dst,
                               float* __restrict__ a_src,
                               float* __restrict__ a_dst) {
    __shared__ float sW[IN_FEAT * HF];
    __shared__ float sAs[HF], sAd[HF];
    for (int i = threadIdx.x; i < IN_FEAT * HF; i += blockDim.x) sW[i] = W[i];
    for (int i = threadIdx.x; i < HF; i += blockDim.x) { sAs[i] = att_src[i]; sAd[i] = att_dst[i]; }
    __syncthreads();

    int gid = blockIdx.x * blockDim.x + threadIdx.x;
    int n = gid / HEADS;
    int h = gid % HEADS;
    if (n >= N_NODES) return;

    float dv[IN_FEAT];
    const float4* dp = (const float4*)(data + (size_t)n * IN_FEAT);
#pragma unroll
    for (int q = 0; q < 4; q++) {
        float4 v = dp[q];
        dv[q*4+0] = v.x; dv[q*4+1] = v.y; dv[q*4+2] = v.z; dv[q*4+3] = v.w;
    }

    float out[OUT_FEAT];
#pragma unroll
    for (int f = 0; f < OUT_FEAT; f++) out[f] = 0.f;
#pragma unroll
    for (int k = 0; k < IN_FEAT; k++) {
        float dk = dv[k];
        const float* wrow = &sW[k * HF + h * OUT_FEAT];
#pragma unroll
        for (int f = 0; f < OUT_FEAT; f++) out[f] = fmaf(dk, wrow[f], out[f]);
    }

    float as = 0.f, ad = 0.f;
#pragma unroll
    for (int f = 0; f < OUT_FEAT; f++) {
        as = fmaf(out[f], sAs[h * OUT_FEAT + f], as);
        ad = fmaf(out[f], sAd[h * OUT_FEAT + f], ad);
    }
    a_src[n * HEADS + h] = as;
    a_dst[n * HEADS + h] = ad;
}

// ---------------------------------------------------------------------------
// K0: per-launch cursor init (gcursor[b] = b*CAP). No global memsets needed
// anywhere else in the pipeline.
// ---------------------------------------------------------------------------
__global__ void init_cursors(int* __restrict__ gcursor) {
    int b = blockIdx.x * blockDim.x + threadIdx.x;
    if (b < NB) gcursor[b] = b * CAP;
}

// ---------------------------------------------------------------------------
// K2: partition real edges into NB dst-range buckets.
// Per block: LDS histogram -> one global atomic reservation per (block,bucket)
// (128*4096 = 524k small atomics, vs 1.6M line-RMWs in the old scatter path)
// -> stable intra-block scatter via LDS cursors.
// spack[pos] = src | (d_local << 17)   (src < 2^17, d_local < 25 -> 22 bits)
// ---------------------------------------------------------------------------
__global__ void partition_edges(const int* __restrict__ esrc,
                                const int* __restrict__ edst,
                                int* __restrict__ gcursor,
                                unsigned int* __restrict__ spack) {
    __shared__ int hist[NB];   // 16 KB (doubles as intra-block cursor)
    __shared__ int base[NB];   // 16 KB
    const int chunk = (N_EDGES + NBLK_PART - 1) / NBLK_PART;   // 12500
    const int e0 = blockIdx.x * chunk;
    const int e1 = min(e0 + chunk, N_EDGES);

    for (int j = threadIdx.x; j < NB; j += blockDim.x) hist[j] = 0;
    __syncthreads();
    for (int e = e0 + threadIdx.x; e < e1; e += blockDim.x) {
        int d = edst[e];
        atomicAdd(&hist[d / NPB], 1);
    }
    __syncthreads();
    for (int j = threadIdx.x; j < NB; j += blockDim.x) {
        int c = hist[j];
        base[j] = c ? atomicAdd(&gcursor[j], c) : 0;
    }
    __syncthreads();
    for (int j = threadIdx.x; j < NB; j += blockDim.x) hist[j] = 0;
    __syncthreads();
    for (int e = e0 + threadIdx.x; e < e1; e += blockDim.x) {
        int s = esrc[e], d = edst[e];
        int b = d / NPB;
        int r = atomicAdd(&hist[b], 1);
        int pos = base[b] + r;
        if (pos < (b + 1) * CAP)   // paranoia guard (statistically unreachable)
            spack[pos] = (unsigned int)s | ((unsigned int)(d - b * NPB) << 17);
    }
}

// ---------------------------------------------------------------------------
// K5: bucket aggregate — the whole GAT edge math with LDS-only accumulation.
// One block per bucket (25 dst nodes). 16-lane groups, lane f = feature f.
// Per edge: gather a_src[s] (2.4MB, L2-hot), data[s] row (6.4MB, L2/L3),
// recompute x[s,h,f] from per-lane W columns, exp on lanes 0-5 + shfl
// broadcast, ds_add_f32 into per-head num/den/cnum in LDS.
// Self-loops processed inline (no concat needed). Finalize (normalize, mean
// over heads, selu, bias, coord override) fused; outputs written once.
// Zero global scatter atomics.
// ---------------------------------------------------------------------------
__global__ void bucket_aggregate(const int* __restrict__ gcursor,
                                 const unsigned int* __restrict__ spack,
                                 const float* __restrict__ data,
                                 const float* __restrict__ W,
                                 const float* __restrict__ a_src,
                                 const float* __restrict__ a_dst,
                                 const float* __restrict__ bias,
                                 float* __restrict__ out) {
    const int b = blockIdx.x;
    const int n0 = b * NPB;
    if (n0 >= N_NODES) return;
    const int nn = min(NPB, N_NODES - n0);

    __shared__ float num[NPB * DLS];   // [dl][h*16+f], stride 100 (bank spread)
    __shared__ float den[NPB * 8];     // [dl][h], stride 8
    __shared__ float cnum[NPB * 16];   // [dl][h*2+c], stride 16
    for (int j = threadIdx.x; j < NPB * DLS; j += 256) num[j] = 0.f;
    for (int j = threadIdx.x; j < NPB * 8;   j += 256) den[j] = 0.f;
    for (int j = threadIdx.x; j < NPB * 16;  j += 256) cnum[j] = 0.f;
    __syncthreads();

    const int f = threadIdx.x & 15;
    const int g = threadIdx.x >> 4;    // 16 edge-groups per block

    // Per-lane W columns: wreg[h*16+k] = W[k][h*16+f]
    float wreg[96];
#pragma unroll
    for (int h = 0; h < HEADS; h++)
#pragma unroll
        for (int k = 0; k < IN_FEAT; k++)
            wreg[h * 16 + k] = W[k * HF + h * OUT_FEAT + f];

    const int ecnt = gcursor[b] - b * CAP;

    auto process = [&](int s, int dl) {
        float ex = 0.f;
        if (f < HEADS) {
            float e = a_src[s * HEADS + f] + a_dst[(n0 + dl) * HEADS + f];
            e = e > 0.f ? e : 0.2f * e;            // leaky relu
            ex = __expf(e);
            atomicAdd(&den[dl * 8 + f], ex);
        }
        float xh[HEADS];
#pragma unroll
        for (int h = 0; h < HEADS; h++) xh[h] = 0.f;
        float c0 = 0.f, c1 = 0.f;
        const float4* dp = (const float4*)(data + (size_t)s * IN_FEAT);
#pragma unroll
        for (int q = 0; q < 4; q++) {
            float4 v = dp[q];
            if (q == 0) { c0 = v.x; c1 = v.y; }
#pragma unroll
            for (int h = 0; h < HEADS; h++) {
                xh[h] = fmaf(v.x, wreg[h * 16 + q * 4 + 0], xh[h]);
                xh[h] = fmaf(v.y, wreg[h * 16 + q * 4 + 1], xh[h]);
                xh[h] = fmaf(v.z, wreg[h * 16 + q * 4 + 2], xh[h]);
                xh[h] = fmaf(v.w, wreg[h * 16 + q * 4 + 3], xh[h]);
            }
        }
        float cc = (f == 0) ? c0 : c1;
#pragma unroll
        for (int h = 0; h < HEADS; h++) {
            float eh = __shfl(ex, h, 16);
            atomicAdd(&num[dl * DLS + h * 16 + f], xh[h] * eh);
            if (f < 2) atomicAdd(&cnum[dl * 16 + h * 2 + f], cc * eh);
        }
    };

    // self-loops (one per dst node in this bucket)
    for (int dl = g; dl < nn; dl += 16) process(n0 + dl, dl);
    // real edges
    for (int i = g; i < ecnt; i += 16) {
        unsigned int p = spack[b * CAP + i];
        process((int)(p & 0x1FFFFu), (int)(p >> 17));
    }
    __syncthreads();

    // finalize: feat = selu(mean_h(num/den) + bias); coord with overrides
    const float sc = 1.0507009873554805f;
    const float al = 1.6732632423543772f;
    for (int dl = g; dl < nn; dl += 16) {
        int n = n0 + dl;
        float acc = 0.f, ca = 0.f;
#pragma unroll
        for (int h = 0; h < HEADS; h++) {
            float r = __builtin_amdgcn_rcpf(den[dl * 8 + h] + 1e-16f);
            acc = fmaf(num[dl * DLS + h * 16 + f], r, acc);
            if (f < 2) ca = fmaf(cnum[dl * 16 + h * 2 + f], r, ca);
        }
        float v = acc * (1.f / 6.f) + bias[f];
        v = v > 0.f ? sc * v : sc * al * (__expf(v) - 1.f);
        out[2 * N_NODES + (size_t)n * OUT_FEAT + f] = v;

        if (f < 2) {
            float c = ca * (0.2f / 6.f);
            float key = data[(size_t)n * IN_FEAT + f];
            if (key == 1.0f)      c = 1.0f;
            else if (key == 0.0f) c = 0.0f;
            out[n * 2 + f] = c;
        }
    }
}

// ---------------------------------------------------------------------------
// Workspace layout (float offsets):
//   [0, 600000)        a_src   (N*6)
//   [600000, 1200000)  a_dst   (N*6)
//   [1200000, 1204096) gcursor (NB ints)
//   [1204096, ...)     spack   (NB*CAP uints = 8.9 MB)
// Total ~13.9 MB. No global memsets required.
// ---------------------------------------------------------------------------
extern "C" void kernel_launch(void* const* d_in, const int* in_sizes, int n_in,
                              void* d_out, int out_size, void* d_ws, size_t ws_size,
                              hipStream_t stream) {
    const float* data    = (const float*)d_in[0];
    const int*   eidx    = (const int*)d_in[1];      // int32 on device
    const float* W       = (const float*)d_in[2];
    const float* att_src = (const float*)d_in[3];
    const float* att_dst = (const float*)d_in[4];
    const float* bias    = (const float*)d_in[5];
    float*       out     = (float*)d_out;
    float*       ws      = (float*)d_ws;

    float*        a_src   = ws;
    float*        a_dst   = ws + 600000;
    int*          gcursor = (int*)(ws + 1200000);
    unsigned int* spack   = (unsigned int*)(ws + 1204096);

    init_cursors<<<(NB + 255) / 256, 256, 0, stream>>>(gcursor);

    {
        int total = N_NODES * HEADS;
        node_transform<<<(total + 255) / 256, 256, 0, stream>>>(
            data, W, att_src, att_dst, a_src, a_dst);
    }

    partition_edges<<<NBLK_PART, 256, 0, stream>>>(
        eidx, eidx + N_EDGES, gcursor, spack);

    bucket_aggregate<<<NB, 256, 0, stream>>>(
        gcursor, spack, data, W, a_src, a_dst, bias, out);
}

// Round 7
// 461.475 us; speedup vs baseline: 2.4038x; 2.4038x over previous
//
#include <hip/hip_runtime.h>
#include <math.h>

#define N_NODES 100000
#define N_EDGES 1600000
#define IN_FEAT 16
#define OUT_FEAT 16
#define HEADS 6
#define HF 96                 // HEADS*OUT_FEAT

// Bucketed-aggregate geometry:
#define NB 4096               // buckets
#define NPB 25                // nodes per bucket (4096*25 = 102400 >= 100000)
#define CAP 544               // per-bucket edge capacity (mean 400, +7.2 sigma)
#define NBLK_PART 128         // partition blocks

// ---------------------------------------------------------------------------
// K1: attention logits a_src/a_dst per (node, head). x not materialized
// (R5 lesson: recompute from 64B data row beats gathering a >L2 x array).
// ---------------------------------------------------------------------------
__global__ void node_transform(const float* __restrict__ data,
                               const float* __restrict__ W,
                               const float* __restrict__ att_src,
                               const float* __restrict__ att_dst,
                               float* __restrict__ a_src,
                               float* __restrict__ a_dst) {
    __shared__ float sW[IN_FEAT * HF];
    __shared__ float sAs[HF], sAd[HF];
    for (int i = threadIdx.x; i < IN_FEAT * HF; i += blockDim.x) sW[i] = W[i];
    for (int i = threadIdx.x; i < HF; i += blockDim.x) { sAs[i] = att_src[i]; sAd[i] = att_dst[i]; }
    __syncthreads();

    int gid = blockIdx.x * blockDim.x + threadIdx.x;
    int n = gid / HEADS;
    int h = gid % HEADS;
    if (n >= N_NODES) return;

    float dv[IN_FEAT];
    const float4* dp = (const float4*)(data + (size_t)n * IN_FEAT);
#pragma unroll
    for (int q = 0; q < 4; q++) {
        float4 v = dp[q];
        dv[q*4+0] = v.x; dv[q*4+1] = v.y; dv[q*4+2] = v.z; dv[q*4+3] = v.w;
    }

    float out[OUT_FEAT];
#pragma unroll
    for (int f = 0; f < OUT_FEAT; f++) out[f] = 0.f;
#pragma unroll
    for (int k = 0; k < IN_FEAT; k++) {
        float dk = dv[k];
        const float* wrow = &sW[k * HF + h * OUT_FEAT];
#pragma unroll
        for (int f = 0; f < OUT_FEAT; f++) out[f] = fmaf(dk, wrow[f], out[f]);
    }

    float as = 0.f, ad = 0.f;
#pragma unroll
    for (int f = 0; f < OUT_FEAT; f++) {
        as = fmaf(out[f], sAs[h * OUT_FEAT + f], as);
        ad = fmaf(out[f], sAd[h * OUT_FEAT + f], ad);
    }
    a_src[n * HEADS + h] = as;
    a_dst[n * HEADS + h] = ad;
}

// ---------------------------------------------------------------------------
// K0: cursor init (gcursor[b] = b*CAP); no other global zeroing needed.
// ---------------------------------------------------------------------------
__global__ void init_cursors(int* __restrict__ gcursor) {
    int b = blockIdx.x * blockDim.x + threadIdx.x;
    if (b < NB) gcursor[b] = b * CAP;
}

// ---------------------------------------------------------------------------
// K2: partition real edges into NB dst-range buckets (unchanged from R6 —
// it never showed in the top-5, so it's cheap).
// spack[pos] = src | (d_local << 17)
// ---------------------------------------------------------------------------
__global__ void partition_edges(const int* __restrict__ esrc,
                                const int* __restrict__ edst,
                                int* __restrict__ gcursor,
                                unsigned int* __restrict__ spack) {
    __shared__ int hist[NB];
    __shared__ int base[NB];
    const int chunk = (N_EDGES + NBLK_PART - 1) / NBLK_PART;   // 12500
    const int e0 = blockIdx.x * chunk;
    const int e1 = min(e0 + chunk, N_EDGES);

    for (int j = threadIdx.x; j < NB; j += blockDim.x) hist[j] = 0;
    __syncthreads();
    for (int e = e0 + threadIdx.x; e < e1; e += blockDim.x) {
        int d = edst[e];
        atomicAdd(&hist[d / NPB], 1);          // int LDS atomic: native ds_add
    }
    __syncthreads();
    for (int j = threadIdx.x; j < NB; j += blockDim.x) {
        int c = hist[j];
        base[j] = c ? atomicAdd(&gcursor[j], c) : 0;
    }
    __syncthreads();
    for (int j = threadIdx.x; j < NB; j += blockDim.x) hist[j] = 0;
    __syncthreads();
    for (int e = e0 + threadIdx.x; e < e1; e += blockDim.x) {
        int s = esrc[e], d = edst[e];
        int b = d / NPB;
        int r = atomicAdd(&hist[b], 1);
        int pos = base[b] + r;
        if (pos < (b + 1) * CAP)   // statistically unreachable guard
            spack[pos] = (unsigned int)s | ((unsigned int)(d - b * NPB) << 17);
    }
}

// ---------------------------------------------------------------------------
// K3: bucket aggregate, v2 — NO floating-point atomics anywhere.
// R6's fp32 LDS atomicAdd compiled to a CAS retry loop (9.7% VALUBusy,
// 90% lgkm-stall). v2: bin the bucket's edges into per-node CSR lists in
// LDS using native INT LDS atomics, then each 16-lane group walks one
// node's contiguous list accumulating num/den/cnum in REGISTERS, and
// writes the finalized outputs (selu, coord overrides) directly. One
// coalesced store per output element; a_dst hoisted per node; self-loop
// folded in as iteration -1.
// ---------------------------------------------------------------------------
__global__ void bucket_aggregate(const int* __restrict__ gcursor,
                                 const unsigned int* __restrict__ spack,
                                 const float* __restrict__ data,
                                 const float* __restrict__ W,
                                 const float* __restrict__ a_src,
                                 const float* __restrict__ a_dst,
                                 const float* __restrict__ bias,
                                 float* __restrict__ out) {
    const int b = blockIdx.x;
    const int n0 = b * NPB;
    if (n0 >= N_NODES) return;
    const int nn = min(NPB, N_NODES - n0);

    __shared__ unsigned int olist[CAP];     // per-node-ordered src indices
    __shared__ int cnt[NPB];
    __shared__ int start[NPB + 1];
    __shared__ int cur[NPB];

    const int tid = threadIdx.x;
    const int f = tid & 15;
    const int g = tid >> 4;                 // 16 groups of 16 lanes

    // Per-lane W columns: wreg[h*16+k] = W[k][h*16+f]
    float wreg[96];
#pragma unroll
    for (int h = 0; h < HEADS; h++)
#pragma unroll
        for (int k = 0; k < IN_FEAT; k++)
            wreg[h * 16 + k] = W[k * HF + h * OUT_FEAT + f];

    const int ecnt = gcursor[b] - b * CAP;

    // ---- bin to per-node CSR in LDS (int atomics only) ----
    for (int j = tid; j < NPB; j += 256) cnt[j] = 0;
    __syncthreads();
    for (int i = tid; i < ecnt; i += 256)
        atomicAdd(&cnt[spack[b * CAP + i] >> 17], 1);
    __syncthreads();
    if (tid == 0) {
        int r = 0;
        for (int j = 0; j < NPB; j++) { start[j] = r; r += cnt[j]; }
        start[NPB] = r;
    }
    __syncthreads();
    for (int j = tid; j < NPB; j += 256) cur[j] = start[j];
    __syncthreads();
    for (int i = tid; i < ecnt; i += 256) {
        unsigned int p = spack[b * CAP + i];
        int dl = (int)(p >> 17);
        int pos = atomicAdd(&cur[dl], 1);
        olist[pos] = p & 0x1FFFFu;
    }
    __syncthreads();

    // ---- per-node register accumulation ----
    const float sc = 1.0507009873554805f;
    const float al = 1.6732632423543772f;

    for (int dl = g; dl < nn; dl += 16) {
        const int n = n0 + dl;
        const float adf = (f < HEADS) ? a_dst[n * HEADS + f] : 0.f;
        const int s0 = start[dl];
        const int s1 = start[dl] + cnt[dl];

        float num[HEADS], cn[HEADS];
#pragma unroll
        for (int h = 0; h < HEADS; h++) { num[h] = 0.f; cn[h] = 0.f; }
        float den = 0.f;

        for (int k = s0 - 1; k < s1; ++k) {       // k == s0-1: self-loop
            const int s = (k < s0) ? n : (int)olist[k];

            float ex = 0.f;
            if (f < HEADS) {
                float e = a_src[s * HEADS + f] + adf;
                e = e > 0.f ? e : 0.2f * e;       // leaky relu
                ex = __expf(e);
                den += ex;
            }

            float xh[HEADS];
#pragma unroll
            for (int h = 0; h < HEADS; h++) xh[h] = 0.f;
            float c01 = 0.f;
            const float4* dp = (const float4*)(data + (size_t)s * IN_FEAT);
#pragma unroll
            for (int q = 0; q < 4; q++) {
                float4 v = dp[q];
                if (q == 0) c01 = (f == 0) ? v.x : v.y;
#pragma unroll
                for (int h = 0; h < HEADS; h++) {
                    xh[h] = fmaf(v.x, wreg[h * 16 + q * 4 + 0], xh[h]);
                    xh[h] = fmaf(v.y, wreg[h * 16 + q * 4 + 1], xh[h]);
                    xh[h] = fmaf(v.z, wreg[h * 16 + q * 4 + 2], xh[h]);
                    xh[h] = fmaf(v.w, wreg[h * 16 + q * 4 + 3], xh[h]);
                }
            }
#pragma unroll
            for (int h = 0; h < HEADS; h++) {
                float eh = __shfl(ex, h, 16);
                num[h] = fmaf(xh[h], eh, num[h]);
                if (f < 2) cn[h] = fmaf(c01, eh, cn[h]);
            }
        }

        // normalize + mean over heads
        float acc = 0.f, ca = 0.f;
#pragma unroll
        for (int h = 0; h < HEADS; h++) {
            float dh = __shfl(den, h, 16);
            float r = __builtin_amdgcn_rcpf(dh + 1e-16f);
            acc = fmaf(num[h], r, acc);
            ca  = fmaf(cn[h],  r, ca);
        }

        float v = acc * (1.f / 6.f) + bias[f];
        v = v > 0.f ? sc * v : sc * al * (__expf(v) - 1.f);
        out[2 * N_NODES + (size_t)n * OUT_FEAT + f] = v;

        if (f < 2) {
            float c = ca * (0.2f / 6.f);
            float key = data[(size_t)n * IN_FEAT + f];
            if (key == 1.0f)      c = 1.0f;
            else if (key == 0.0f) c = 0.0f;
            out[n * 2 + f] = c;
        }
    }
}

// ---------------------------------------------------------------------------
// Workspace layout (float offsets):
//   [0, 600000)        a_src   (N*6)
//   [600000, 1200000)  a_dst   (N*6)
//   [1200000, 1204096) gcursor (NB ints)
//   [1204096, ...)     spack   (NB*CAP uints = 8.9 MB)
// ---------------------------------------------------------------------------
extern "C" void kernel_launch(void* const* d_in, const int* in_sizes, int n_in,
                              void* d_out, int out_size, void* d_ws, size_t ws_size,
                              hipStream_t stream) {
    const float* data    = (const float*)d_in[0];
    const int*   eidx    = (const int*)d_in[1];      // int32 on device
    const float* W       = (const float*)d_in[2];
    const float* att_src = (const float*)d_in[3];
    const float* att_dst = (const float*)d_in[4];
    const float* bias    = (const float*)d_in[5];
    float*       out     = (float*)d_out;
    float*       ws      = (float*)d_ws;

    float*        a_src   = ws;
    float*        a_dst   = ws + 600000;
    int*          gcursor = (int*)(ws + 1200000);
    unsigned int* spack   = (unsigned int*)(ws + 1204096);

    init_cursors<<<(NB + 255) / 256, 256, 0, stream>>>(gcursor);

    {
        int total = N_NODES * HEADS;
        node_transform<<<(total + 255) / 256, 256, 0, stream>>>(
            data, W, att_src, att_dst, a_src, a_dst);
    }

    partition_edges<<<NBLK_PART, 256, 0, stream>>>(
        eidx, eidx + N_EDGES, gcursor, spack);

    bucket_aggregate<<<NB, 256, 0, stream>>>(
        gcursor, spack, data, W, a_src, a_dst, bias, out);
}

// Round 8
// 184.172 us; speedup vs baseline: 6.0231x; 2.5057x over previous
//
#include <hip/hip_runtime.h>
#include <math.h>

#define N_NODES 100000
#define N_EDGES 1600000
#define IN_FEAT 16
#define OUT_FEAT 16
#define HEADS 6
#define HF 96                 // HEADS*OUT_FEAT

// Bucketed-aggregate geometry:
#define NB 4096               // buckets
#define NPB 25                // nodes per bucket (4096*25 = 102400 >= 100000)
#define CAP 544               // per-bucket edge capacity (mean ~400, +7 sigma)
#define NBLK_PART 128         // partition blocks

// ---------------------------------------------------------------------------
// K1: attention logits a_src/a_dst per (node, head).
// ---------------------------------------------------------------------------
__global__ void node_transform(const float* __restrict__ data,
                               const float* __restrict__ W,
                               const float* __restrict__ att_src,
                               const float* __restrict__ att_dst,
                               float* __restrict__ a_src,
                               float* __restrict__ a_dst) {
    __shared__ float sW[IN_FEAT * HF];
    __shared__ float sAs[HF], sAd[HF];
    for (int i = threadIdx.x; i < IN_FEAT * HF; i += blockDim.x) sW[i] = W[i];
    for (int i = threadIdx.x; i < HF; i += blockDim.x) { sAs[i] = att_src[i]; sAd[i] = att_dst[i]; }
    __syncthreads();

    int gid = blockIdx.x * blockDim.x + threadIdx.x;
    int n = gid / HEADS;
    int h = gid % HEADS;
    if (n >= N_NODES) return;

    float dv[IN_FEAT];
    const float4* dp = (const float4*)(data + (size_t)n * IN_FEAT);
#pragma unroll
    for (int q = 0; q < 4; q++) {
        float4 v = dp[q];
        dv[q*4+0] = v.x; dv[q*4+1] = v.y; dv[q*4+2] = v.z; dv[q*4+3] = v.w;
    }

    float out[OUT_FEAT];
#pragma unroll
    for (int f = 0; f < OUT_FEAT; f++) out[f] = 0.f;
#pragma unroll
    for (int k = 0; k < IN_FEAT; k++) {
        float dk = dv[k];
        const float* wrow = &sW[k * HF + h * OUT_FEAT];
#pragma unroll
        for (int f = 0; f < OUT_FEAT; f++) out[f] = fmaf(dk, wrow[f], out[f]);
    }

    float as = 0.f, ad = 0.f;
#pragma unroll
    for (int f = 0; f < OUT_FEAT; f++) {
        as = fmaf(out[f], sAs[h * OUT_FEAT + f], as);
        ad = fmaf(out[f], sAd[h * OUT_FEAT + f], ad);
    }
    a_src[n * HEADS + h] = as;
    a_dst[n * HEADS + h] = ad;
}

// ---------------------------------------------------------------------------
// K0: cursor init.
// ---------------------------------------------------------------------------
__global__ void init_cursors(int* __restrict__ gcursor) {
    int b = blockIdx.x * blockDim.x + threadIdx.x;
    if (b < NB) gcursor[b] = b * CAP;
}

// ---------------------------------------------------------------------------
// K2: partition real edges into NB dst-range buckets.
// spack[pos] = src | (d_local << 17)
// ---------------------------------------------------------------------------
__global__ void partition_edges(const int* __restrict__ esrc,
                                const int* __restrict__ edst,
                                int* __restrict__ gcursor,
                                unsigned int* __restrict__ spack) {
    __shared__ int hist[NB];
    __shared__ int base[NB];
    const int chunk = (N_EDGES + NBLK_PART - 1) / NBLK_PART;   // 12500
    const int e0 = blockIdx.x * chunk;
    const int e1 = min(e0 + chunk, N_EDGES);

    for (int j = threadIdx.x; j < NB; j += blockDim.x) hist[j] = 0;
    __syncthreads();
    for (int e = e0 + threadIdx.x; e < e1; e += blockDim.x) {
        int d = edst[e];
        atomicAdd(&hist[d / NPB], 1);          // native int ds_add
    }
    __syncthreads();
    for (int j = threadIdx.x; j < NB; j += blockDim.x) {
        int c = hist[j];
        base[j] = c ? atomicAdd(&gcursor[j], c) : 0;
    }
    __syncthreads();
    for (int j = threadIdx.x; j < NB; j += blockDim.x) hist[j] = 0;
    __syncthreads();
    for (int e = e0 + threadIdx.x; e < e1; e += blockDim.x) {
        int s = esrc[e], d = edst[e];
        int b = d / NPB;
        int r = atomicAdd(&hist[b], 1);
        int pos = base[b] + r;
        if (pos < (b + 1) * CAP)
            spack[pos] = (unsigned int)s | ((unsigned int)(d - b * NPB) << 17);
    }
}

// ---------------------------------------------------------------------------
// K3 (phase A): per-node weighted-data accumulation. KEY CHANGE vs R7:
// swap summation order — num[h][f] = sum_k W[k][h16+f] * wsum[h][k] where
// wsum[h][k] = sum_e exp_e * data[s_e,k]. Per edge: 1 load + 6 FMA per lane,
// NO W access. The 96x16 W-multiply moves to a dense per-node kernel (K4).
// Coord numerators are wsum[h][0..1] — free.
// ONE WAVE PER NODE (4 edge-slots x 16 features): no intra-wave trip-count
// divergence (R7: 4 nodes/wave ran at max degree), 4 gathers in flight.
// Writes wsn = wsum/den (96 floats/node) + final coords. No fp atomics.
// ---------------------------------------------------------------------------
__global__ void bucket_accumulate(const int* __restrict__ gcursor,
                                  const unsigned int* __restrict__ spack,
                                  const float* __restrict__ data,
                                  const float* __restrict__ a_src,
                                  const float* __restrict__ a_dst,
                                  float* __restrict__ wsn_g,
                                  float* __restrict__ out) {
    const int b = blockIdx.x;
    const int n0 = b * NPB;
    if (n0 >= N_NODES) return;
    const int nn = min(NPB, N_NODES - n0);

    __shared__ unsigned int olist[CAP];
    __shared__ int cnt[NPB];
    __shared__ int start[NPB + 1];
    __shared__ int cur[NPB];

    const int tid  = threadIdx.x;
    const int lane = tid & 63;
    const int slot = lane >> 4;       // 4 edge-slots per wave
    const int f    = lane & 15;       // feature/k index
    const int wv   = tid >> 6;        // wave id (0..3)

    int ecnt = gcursor[b] - b * CAP;
    if (ecnt > CAP) ecnt = CAP;       // statistically unreachable

    // ---- bin to per-node CSR in LDS (int atomics only) ----
    for (int j = tid; j < NPB; j += 256) cnt[j] = 0;
    __syncthreads();
    for (int i = tid; i < ecnt; i += 256)
        atomicAdd(&cnt[spack[b * CAP + i] >> 17], 1);
    __syncthreads();
    if (tid == 0) {
        int r = 0;
        for (int j = 0; j < NPB; j++) { start[j] = r; r += cnt[j]; }
        start[NPB] = r;
    }
    __syncthreads();
    for (int j = tid; j < NPB; j += 256) cur[j] = start[j];
    __syncthreads();
    for (int i = tid; i < ecnt; i += 256) {
        unsigned int p = spack[b * CAP + i];
        int dl = (int)(p >> 17);
        int pos = atomicAdd(&cur[dl], 1);
        olist[pos] = p & 0x1FFFFu;
    }
    __syncthreads();

    // ---- one wave per node ----
    for (int dl = wv; dl < nn; dl += 4) {
        const int n = n0 + dl;
        const float adf = (f < HEADS) ? a_dst[n * HEADS + f] : 0.f;
        const int s0 = start[dl];
        const int T = cnt[dl] + 1;            // +1: self-loop at t==0

        float wsum[HEADS];
#pragma unroll
        for (int h = 0; h < HEADS; h++) wsum[h] = 0.f;
        float den = 0.f;

        for (int t = slot; t < T; t += 4) {
            int s = n;
            if (t > 0) s = (int)olist[s0 + t - 1];

            float ex = 0.f;
            if (f < HEADS) {
                float e = a_src[s * HEADS + f] + adf;
                e = e > 0.f ? e : 0.2f * e;   // leaky relu
                ex = __expf(e);
                den += ex;
            }
            float dv = data[(size_t)s * IN_FEAT + f];
#pragma unroll
            for (int h = 0; h < HEADS; h++) {
                float eh = __shfl(ex, h, 16);
                wsum[h] = fmaf(dv, eh, wsum[h]);
            }
        }

        // reduce the 4 slots
#pragma unroll
        for (int h = 0; h < HEADS; h++) {
            wsum[h] += __shfl_xor(wsum[h], 16, 64);
            wsum[h] += __shfl_xor(wsum[h], 32, 64);
        }
        den += __shfl_xor(den, 16, 64);
        den += __shfl_xor(den, 32, 64);

        float wsn[HEADS];
#pragma unroll
        for (int h = 0; h < HEADS; h++) {
            float dh = __shfl(den, h, 16);
            wsn[h] = wsum[h] * __builtin_amdgcn_rcpf(dh + 1e-16f);
        }

        if (slot == 0) {
#pragma unroll
            for (int h = 0; h < HEADS; h++)
                wsn_g[(size_t)n * HF + h * 16 + f] = wsn[h];
            if (f < 2) {                      // fused coord output
                float cs = 0.f;
#pragma unroll
                for (int h = 0; h < HEADS; h++) cs += wsn[h];
                float c = cs * (0.2f / 6.f);
                float key = data[(size_t)n * IN_FEAT + f];
                if (key == 1.0f)      c = 1.0f;
                else if (key == 0.0f) c = 0.0f;
                out[n * 2 + f] = c;
            }
        }
    }
}

// ---------------------------------------------------------------------------
// K4 (phase B): dense per-node transform. feat[n,f] =
// selu( (1/6) * sum_j wsn[n,j] * M[j][f] + bias[f] ),  M[h*16+k][f] = W[k][h16+f].
// 16 nodes per block staged in LDS; M transposed with pad-100 stride
// (gcd(25,32)=1 -> conflict-free b128 reads). Fully coalesced global I/O.
// ---------------------------------------------------------------------------
__global__ void feat_transform(const float* __restrict__ wsn_g,
                               const float* __restrict__ W,
                               const float* __restrict__ bias,
                               float* __restrict__ out) {
    __shared__ float MT[16 * 100];            // [f][j], padded stride 100
    __shared__ float rows[16 * HF];           // 16 node rows

    const int tid = threadIdx.x;
    for (int idx = tid; idx < 16 * HF; idx += 256) {
        int fcol = idx / HF, r = idx % HF;
        int h = r / 16, k = r % 16;
        MT[fcol * 100 + r] = W[k * HF + h * 16 + fcol];
    }
    const int nb = blockIdx.x * 16;           // 100000 % 16 == 0: no tail
    for (int idx = tid; idx < 16 * HF; idx += 256)
        rows[idx] = wsn_g[(size_t)nb * HF + idx];
    __syncthreads();

    const int nl = tid >> 4;
    const int f  = tid & 15;
    const float4* rv4 = (const float4*)(rows + nl * HF);
    const float4* mv4 = (const float4*)(MT + f * 100);

    float acc = 0.f;
#pragma unroll
    for (int jc = 0; jc < 24; jc++) {
        float4 rv = rv4[jc], mv = mv4[jc];
        acc = fmaf(rv.x, mv.x, acc);
        acc = fmaf(rv.y, mv.y, acc);
        acc = fmaf(rv.z, mv.z, acc);
        acc = fmaf(rv.w, mv.w, acc);
    }

    const float sc = 1.0507009873554805f;
    const float al = 1.6732632423543772f;
    float v = acc * (1.f / 6.f) + bias[f];
    v = v > 0.f ? sc * v : sc * al * (__expf(v) - 1.f);
    out[2 * N_NODES + (size_t)(nb + nl) * OUT_FEAT + f] = v;
}

// ---------------------------------------------------------------------------
// Workspace layout (float offsets):
//   [0, 600000)            a_src   (N*6)
//   [600000, 1200000)      a_dst   (N*6)
//   [1200000, 1204096)     gcursor (NB ints)
//   [1204096, 3432320)     spack   (NB*CAP uints = 8.9 MB)
//   [3432320, 13032320)    wsn     (N*96 = 38.4 MB)
// Total ~52.1 MB.
// ---------------------------------------------------------------------------
extern "C" void kernel_launch(void* const* d_in, const int* in_sizes, int n_in,
                              void* d_out, int out_size, void* d_ws, size_t ws_size,
                              hipStream_t stream) {
    const float* data    = (const float*)d_in[0];
    const int*   eidx    = (const int*)d_in[1];      // int32 on device
    const float* W       = (const float*)d_in[2];
    const float* att_src = (const float*)d_in[3];
    const float* att_dst = (const float*)d_in[4];
    const float* bias    = (const float*)d_in[5];
    float*       out     = (float*)d_out;
    float*       ws      = (float*)d_ws;

    float*        a_src   = ws;
    float*        a_dst   = ws + 600000;
    int*          gcursor = (int*)(ws + 1200000);
    unsigned int* spack   = (unsigned int*)(ws + 1204096);
    float*        wsn_g   = ws + 3432320;

    init_cursors<<<(NB + 255) / 256, 256, 0, stream>>>(gcursor);

    {
        int total = N_NODES * HEADS;
        node_transform<<<(total + 255) / 256, 256, 0, stream>>>(
            data, W, att_src, att_dst, a_src, a_dst);
    }

    partition_edges<<<NBLK_PART, 256, 0, stream>>>(
        eidx, eidx + N_EDGES, gcursor, spack);

    bucket_accumulate<<<NB, 256, 0, stream>>>(
        gcursor, spack, data, a_src, a_dst, wsn_g, out);

    feat_transform<<<N_NODES / 16, 256, 0, stream>>>(
        wsn_g, W, bias, out);
}

// Round 9
// 161.367 us; speedup vs baseline: 6.8743x; 1.1413x over previous
//
#include <hip/hip_runtime.h>
#include <math.h>

#define N_NODES 100000
#define N_EDGES 1600000
#define IN_FEAT 16
#define OUT_FEAT 16
#define HEADS 6
#define HF 96                 // HEADS*OUT_FEAT

// Bucketed-aggregate geometry:
#define NB 4096               // buckets
#define NPB 25                // nodes per bucket (4096*25 = 102400 >= 100000)
#define CAP 544               // per-bucket edge capacity (mean ~400, +7 sigma)
#define NBLK_PART 256         // partition blocks (R8: 128 left half the CUs idle)
#define NT_BLOCKS ((N_NODES * HEADS + 255) / 256)   // 2344 transform blocks

// ---------------------------------------------------------------------------
// K0: cursor init (gcursor[b] = b*CAP).
// ---------------------------------------------------------------------------
__global__ void init_cursors(int* __restrict__ gcursor) {
    int b = blockIdx.x * blockDim.x + threadIdx.x;
    if (b < NB) gcursor[b] = b * CAP;
}

// ---------------------------------------------------------------------------
// K1: prep = partition_edges (blocks [0, NBLK_PART)) + node_transform
// (blocks [NBLK_PART, ...)). The two tasks are independent; fusing them
// overlaps partition's latency-bound scatter with transform's VALU work
// instead of serializing two dispatches. LDS is a union (32 KB partition
// hist/base; transform's 6.9 KB aliases the same block).
// ---------------------------------------------------------------------------
__global__ void prep(const int* __restrict__ esrc,
                     const int* __restrict__ edst,
                     int* __restrict__ gcursor,
                     unsigned int* __restrict__ spack,
                     const float* __restrict__ data,
                     const float* __restrict__ W,
                     const float* __restrict__ att_src,
                     const float* __restrict__ att_dst,
                     float* __restrict__ a_src,
                     float* __restrict__ a_dst) {
    __shared__ int shmem[2 * NB];   // 32 KB

    if (blockIdx.x < NBLK_PART) {
        // ---------------- partition branch ----------------
        int* hist = shmem;
        int* base = shmem + NB;
        const int chunk = (N_EDGES + NBLK_PART - 1) / NBLK_PART;   // 6250
        const int e0 = blockIdx.x * chunk;
        const int e1 = min(e0 + chunk, N_EDGES);

        for (int j = threadIdx.x; j < NB; j += blockDim.x) hist[j] = 0;
        __syncthreads();
        for (int e = e0 + threadIdx.x; e < e1; e += blockDim.x) {
            int d = edst[e];
            atomicAdd(&hist[d / NPB], 1);      // native int ds_add
        }
        __syncthreads();
        for (int j = threadIdx.x; j < NB; j += blockDim.x) {
            int c = hist[j];
            base[j] = c ? atomicAdd(&gcursor[j], c) : 0;
        }
        __syncthreads();
        for (int j = threadIdx.x; j < NB; j += blockDim.x) hist[j] = 0;
        __syncthreads();
        for (int e = e0 + threadIdx.x; e < e1; e += blockDim.x) {
            int s = esrc[e], d = edst[e];
            int b = d / NPB;
            int r = atomicAdd(&hist[b], 1);
            int pos = base[b] + r;
            if (pos < (b + 1) * CAP)           // statistically unreachable
                spack[pos] = (unsigned int)s | ((unsigned int)(d - b * NPB) << 17);
        }
    } else {
        // ---------------- node_transform branch ----------------
        float* sW  = (float*)shmem;            // 1536 floats
        float* sAs = sW + IN_FEAT * HF;        // 96
        float* sAd = sAs + HF;                 // 96
        for (int i = threadIdx.x; i < IN_FEAT * HF; i += blockDim.x) sW[i] = W[i];
        for (int i = threadIdx.x; i < HF; i += blockDim.x) { sAs[i] = att_src[i]; sAd[i] = att_dst[i]; }
        __syncthreads();

        int gid = (blockIdx.x - NBLK_PART) * blockDim.x + threadIdx.x;
        int n = gid / HEADS;
        int h = gid % HEADS;
        if (n >= N_NODES) return;

        float dv[IN_FEAT];
        const float4* dp = (const float4*)(data + (size_t)n * IN_FEAT);
#pragma unroll
        for (int q = 0; q < 4; q++) {
            float4 v = dp[q];
            dv[q*4+0] = v.x; dv[q*4+1] = v.y; dv[q*4+2] = v.z; dv[q*4+3] = v.w;
        }

        float outv[OUT_FEAT];
#pragma unroll
        for (int fo = 0; fo < OUT_FEAT; fo++) outv[fo] = 0.f;
#pragma unroll
        for (int k = 0; k < IN_FEAT; k++) {
            float dk = dv[k];
            const float* wrow = &sW[k * HF + h * OUT_FEAT];
#pragma unroll
            for (int fo = 0; fo < OUT_FEAT; fo++) outv[fo] = fmaf(dk, wrow[fo], outv[fo]);
        }

        float as = 0.f, ad = 0.f;
#pragma unroll
        for (int fo = 0; fo < OUT_FEAT; fo++) {
            as = fmaf(outv[fo], sAs[h * OUT_FEAT + fo], as);
            ad = fmaf(outv[fo], sAd[h * OUT_FEAT + fo], ad);
        }
        a_src[n * HEADS + h] = as;
        a_dst[n * HEADS + h] = ad;
    }
}

// ---------------------------------------------------------------------------
// K2: bucket accumulate + fused per-node W transform.
// Phase A (per edge, 1 load + 6 FMA/lane, summation-swapped):
//   wsum[h][k] = sum_e exp_e * data[s_e,k];  one wave per node, 4 edge
//   slots x 16 features, 2-way unrolled for gather ILP. No fp atomics.
// Phase A writes wsn = wsum/den to LDS (not global — R8's 77 MB round
// trip eliminated). Phase B (block-wide, after one barrier): dense
//   feat[n,f] = selu(1/6 * sum_j wsn[n,j]*MT[f,j] + bias[f])
// with MT staged in LDS (pad-100 stride), float4 reads, coalesced stores.
// ---------------------------------------------------------------------------
__global__ void bucket_accumulate(const int* __restrict__ gcursor,
                                  const unsigned int* __restrict__ spack,
                                  const float* __restrict__ data,
                                  const float* __restrict__ W,
                                  const float* __restrict__ a_src,
                                  const float* __restrict__ a_dst,
                                  const float* __restrict__ bias,
                                  float* __restrict__ out) {
    const int b = blockIdx.x;
    const int n0 = b * NPB;
    if (n0 >= N_NODES) return;
    const int nn = min(NPB, N_NODES - n0);

    __shared__ unsigned int olist[CAP];        // 2.2 KB
    __shared__ int cnt[NPB];
    __shared__ int start[NPB + 1];
    __shared__ int cur[NPB];
    __shared__ float wsn_l[NPB * 100];         // 10 KB, pad stride 100
    __shared__ float MT[16 * 100];             // 6.4 KB, MT[f][j=h*16+k]

    const int tid  = threadIdx.x;
    const int lane = tid & 63;
    const int slot = lane >> 4;       // 4 edge-slots per wave
    const int f    = lane & 15;       // feature/k index
    const int wv   = tid >> 6;        // wave id (0..3)

    // stage MT[f][h*16+k] = W[k*96 + h*16 + f]
    for (int idx = tid; idx < 16 * HF; idx += 256) {
        int fc = idx / HF, r = idx % HF;
        int h = r / 16, k = r % 16;
        MT[fc * 100 + r] = W[k * HF + h * 16 + fc];
    }

    int ecnt = gcursor[b] - b * CAP;
    if (ecnt > CAP) ecnt = CAP;       // statistically unreachable

    // ---- bin to per-node CSR in LDS (int atomics only) ----
    for (int j = tid; j < NPB; j += 256) cnt[j] = 0;
    __syncthreads();
    for (int i = tid; i < ecnt; i += 256)
        atomicAdd(&cnt[spack[b * CAP + i] >> 17], 1);
    __syncthreads();
    if (tid == 0) {
        int r = 0;
        for (int j = 0; j < NPB; j++) { start[j] = r; r += cnt[j]; }
        start[NPB] = r;
    }
    __syncthreads();
    for (int j = tid; j < NPB; j += 256) cur[j] = start[j];
    __syncthreads();
    for (int i = tid; i < ecnt; i += 256) {
        unsigned int p = spack[b * CAP + i];
        int dl = (int)(p >> 17);
        int pos = atomicAdd(&cur[dl], 1);
        olist[pos] = p & 0x1FFFFu;
    }
    __syncthreads();

    // ---- phase A: one wave per node, 2-way unrolled edge loop ----
    for (int dl = wv; dl < nn; dl += 4) {
        const int n = n0 + dl;
        const float adf = (f < HEADS) ? a_dst[n * HEADS + f] : 0.f;
        const int s0 = start[dl];
        const int T = cnt[dl] + 1;            // +1: self-loop at t==0

        float wsum[HEADS];
#pragma unroll
        for (int h = 0; h < HEADS; h++) wsum[h] = 0.f;
        float den = 0.f;

        int t = slot;
        for (; t + 4 < T; t += 8) {           // two edges in flight
            int sA = (t == 0) ? n : (int)olist[s0 + t - 1];
            int sB = (int)olist[s0 + t + 3];

            float exA = 0.f, exB = 0.f;
            if (f < HEADS) {
                float eA = a_src[sA * HEADS + f] + adf;
                float eB = a_src[sB * HEADS + f] + adf;
                eA = eA > 0.f ? eA : 0.2f * eA;
                eB = eB > 0.f ? eB : 0.2f * eB;
                exA = __expf(eA); exB = __expf(eB);
                den += exA + exB;
            }
            float dvA = data[(size_t)sA * IN_FEAT + f];
            float dvB = data[(size_t)sB * IN_FEAT + f];
#pragma unroll
            for (int h = 0; h < HEADS; h++) {
                wsum[h] = fmaf(dvA, __shfl(exA, h, 16), wsum[h]);
                wsum[h] = fmaf(dvB, __shfl(exB, h, 16), wsum[h]);
            }
        }
        for (; t < T; t += 4) {               // tail
            int s = (t == 0) ? n : (int)olist[s0 + t - 1];
            float ex = 0.f;
            if (f < HEADS) {
                float e = a_src[s * HEADS + f] + adf;
                e = e > 0.f ? e : 0.2f * e;
                ex = __expf(e);
                den += ex;
            }
            float dv = data[(size_t)s * IN_FEAT + f];
#pragma unroll
            for (int h = 0; h < HEADS; h++)
                wsum[h] = fmaf(dv, __shfl(ex, h, 16), wsum[h]);
        }

        // reduce the 4 slots
#pragma unroll
        for (int h = 0; h < HEADS; h++) {
            wsum[h] += __shfl_xor(wsum[h], 16, 64);
            wsum[h] += __shfl_xor(wsum[h], 32, 64);
        }
        den += __shfl_xor(den, 16, 64);
        den += __shfl_xor(den, 32, 64);

        if (slot == 0) {
            float wsn[HEADS];
            float cs = 0.f;
#pragma unroll
            for (int h = 0; h < HEADS; h++) {
                float dh = __shfl(den, h, 16);
                wsn[h] = wsum[h] * __builtin_amdgcn_rcpf(dh + 1e-16f);
                cs += wsn[h];
                wsn_l[dl * 100 + h * 16 + f] = wsn[h];
            }
            if (f < 2) {                      // fused coord output
                float c = cs * (0.2f / 6.f);
                float key = data[(size_t)n * IN_FEAT + f];
                if (key == 1.0f)      c = 1.0f;
                else if (key == 0.0f) c = 0.0f;
                out[n * 2 + f] = c;
            }
        }
    }
    __syncthreads();

    // ---- phase B: dense per-node transform from LDS ----
    const float sc = 1.0507009873554805f;
    const float al = 1.6732632423543772f;
    for (int task = tid; task < nn * 16; task += 256) {
        int dl = task >> 4, fo = task & 15;
        const float4* rv4 = (const float4*)(wsn_l + dl * 100);
        const float4* mv4 = (const float4*)(MT + fo * 100);
        float acc = 0.f;
#pragma unroll
        for (int jc = 0; jc < 24; jc++) {
            float4 rv = rv4[jc], mv = mv4[jc];
            acc = fmaf(rv.x, mv.x, acc);
            acc = fmaf(rv.y, mv.y, acc);
            acc = fmaf(rv.z, mv.z, acc);
            acc = fmaf(rv.w, mv.w, acc);
        }
        float v = acc * (1.f / 6.f) + bias[fo];
        v = v > 0.f ? sc * v : sc * al * (__expf(v) - 1.f);
        out[2 * N_NODES + (size_t)(n0 + dl) * OUT_FEAT + fo] = v;
    }
}

// ---------------------------------------------------------------------------
// Workspace layout (float offsets):
//   [0, 600000)            a_src   (N*6)
//   [600000, 1200000)      a_dst   (N*6)
//   [1200000, 1204096)     gcursor (NB ints)
//   [1204096, 3432320)     spack   (NB*CAP uints = 8.9 MB)
// Total ~13.7 MB.
// ---------------------------------------------------------------------------
extern "C" void kernel_launch(void* const* d_in, const int* in_sizes, int n_in,
                              void* d_out, int out_size, void* d_ws, size_t ws_size,
                              hipStream_t stream) {
    const float* data    = (const float*)d_in[0];
    const int*   eidx    = (const int*)d_in[1];      // int32 on device
    const float* W       = (const float*)d_in[2];
    const float* att_src = (const float*)d_in[3];
    const float* att_dst = (const float*)d_in[4];
    const float* bias    = (const float*)d_in[5];
    float*       out     = (float*)d_out;
    float*       ws      = (float*)d_ws;

    float*        a_src   = ws;
    float*        a_dst   = ws + 600000;
    int*          gcursor = (int*)(ws + 1200000);
    unsigned int* spack   = (unsigned int*)(ws + 1204096);

    init_cursors<<<(NB + 255) / 256, 256, 0, stream>>>(gcursor);

    prep<<<NBLK_PART + NT_BLOCKS, 256, 0, stream>>>(
        eidx, eidx + N_EDGES, gcursor, spack,
        data, W, att_src, att_dst, a_src, a_dst);

    bucket_accumulate<<<NB, 256, 0, stream>>>(
        gcursor, spack, data, W, a_src, a_dst, bias, out);
}

// Round 10
// 159.864 us; speedup vs baseline: 6.9389x; 1.0094x over previous
//
#include <hip/hip_runtime.h>
#include <hip/hip_fp16.h>
#include <math.h>

#define N_NODES 100000
#define N_EDGES 1600000
#define E_TOT (N_EDGES + N_NODES)   // self-loops injected as virtual edges
#define IN_FEAT 16
#define OUT_FEAT 16
#define HEADS 6
#define HF 96                 // HEADS*OUT_FEAT

// Bucketed-aggregate geometry:
#define NB 4096               // buckets
#define NPB 25                // nodes per bucket (4096*25 = 102400 >= 100000)
#define CAP 576               // per-bucket capacity: mean 415.6 (incl self), sigma 19.8 -> +8.1 sigma
#define NBLK_PART 256         // partition blocks
#define NT_BLOCKS ((N_NODES * HEADS + 255) / 256)

// ---------------------------------------------------------------------------
// K0: cursor init (gcursor[b] = b*CAP).
// ---------------------------------------------------------------------------
__global__ void init_cursors(int* __restrict__ gcursor) {
    int b = blockIdx.x * blockDim.x + threadIdx.x;
    if (b < NB) gcursor[b] = b * CAP;
}

// ---------------------------------------------------------------------------
// K1: prep = partition (blocks [0,NBLK_PART)) + node_transform (rest).
// Partition now covers E_TOT with virtual self-loop edges (e>=N_EDGES ->
// s=d=e-N_EDGES), so the aggregate loop has NO self-loop special case.
// Transform branch additionally emits data_f16 (N x 16 half, 3.2 MB — fits
// per-XCD L2; halves phase-A gather bytes; f16 rel err 0.05%).
// spack[pos] = src | (d_local << 17)
// ---------------------------------------------------------------------------
__global__ void prep(const int* __restrict__ esrc,
                     const int* __restrict__ edst,
                     int* __restrict__ gcursor,
                     unsigned int* __restrict__ spack,
                     const float* __restrict__ data,
                     const float* __restrict__ W,
                     const float* __restrict__ att_src,
                     const float* __restrict__ att_dst,
                     float* __restrict__ a_src,
                     float* __restrict__ a_dst,
                     unsigned short* __restrict__ data_f16) {
    __shared__ int shmem[2 * NB];   // 32 KB

    if (blockIdx.x < NBLK_PART) {
        // ---------------- partition branch ----------------
        int* hist = shmem;
        int* base = shmem + NB;
        const int chunk = (E_TOT + NBLK_PART - 1) / NBLK_PART;   // 6641
        const int e0 = blockIdx.x * chunk;
        const int e1 = min(e0 + chunk, E_TOT);

        for (int j = threadIdx.x; j < NB; j += blockDim.x) hist[j] = 0;
        __syncthreads();
        for (int e = e0 + threadIdx.x; e < e1; e += blockDim.x) {
            int d = (e < N_EDGES) ? edst[e] : (e - N_EDGES);
            atomicAdd(&hist[d / NPB], 1);      // native int ds_add
        }
        __syncthreads();
        for (int j = threadIdx.x; j < NB; j += blockDim.x) {
            int c = hist[j];
            base[j] = c ? atomicAdd(&gcursor[j], c) : 0;
        }
        __syncthreads();
        for (int j = threadIdx.x; j < NB; j += blockDim.x) hist[j] = 0;
        __syncthreads();
        for (int e = e0 + threadIdx.x; e < e1; e += blockDim.x) {
            int s, d;
            if (e < N_EDGES) { s = esrc[e]; d = edst[e]; }
            else             { s = d = e - N_EDGES; }
            int b = d / NPB;
            int r = atomicAdd(&hist[b], 1);
            int pos = base[b] + r;
            if (pos < (b + 1) * CAP)           // statistically unreachable
                spack[pos] = (unsigned int)s | ((unsigned int)(d - b * NPB) << 17);
        }
    } else {
        // ---------------- node_transform branch ----------------
        float* sW  = (float*)shmem;            // 1536 floats
        float* sAs = sW + IN_FEAT * HF;        // 96
        float* sAd = sAs + HF;                 // 96
        for (int i = threadIdx.x; i < IN_FEAT * HF; i += blockDim.x) sW[i] = W[i];
        for (int i = threadIdx.x; i < HF; i += blockDim.x) { sAs[i] = att_src[i]; sAd[i] = att_dst[i]; }
        __syncthreads();

        int gid = (blockIdx.x - NBLK_PART) * blockDim.x + threadIdx.x;
        int n = gid / HEADS;
        int h = gid % HEADS;
        if (n >= N_NODES) return;

        float dv[IN_FEAT];
        const float4* dp = (const float4*)(data + (size_t)n * IN_FEAT);
#pragma unroll
        for (int q = 0; q < 4; q++) {
            float4 v = dp[q];
            dv[q*4+0] = v.x; dv[q*4+1] = v.y; dv[q*4+2] = v.z; dv[q*4+3] = v.w;
        }

        // emit f16 copy of the row (threads h=0..3 each pack 4 halves)
        if (h < 4) {
            unsigned int lo = (unsigned int)__half_as_ushort(__float2half_rn(dv[h*4+0]))
                            | ((unsigned int)__half_as_ushort(__float2half_rn(dv[h*4+1])) << 16);
            unsigned int hi = (unsigned int)__half_as_ushort(__float2half_rn(dv[h*4+2]))
                            | ((unsigned int)__half_as_ushort(__float2half_rn(dv[h*4+3])) << 16);
            uint2 pk; pk.x = lo; pk.y = hi;
            *(uint2*)(data_f16 + (size_t)n * IN_FEAT + h * 4) = pk;
        }

        float outv[OUT_FEAT];
#pragma unroll
        for (int fo = 0; fo < OUT_FEAT; fo++) outv[fo] = 0.f;
#pragma unroll
        for (int k = 0; k < IN_FEAT; k++) {
            float dk = dv[k];
            const float* wrow = &sW[k * HF + h * OUT_FEAT];
#pragma unroll
            for (int fo = 0; fo < OUT_FEAT; fo++) outv[fo] = fmaf(dk, wrow[fo], outv[fo]);
        }

        float as = 0.f, ad = 0.f;
#pragma unroll
        for (int fo = 0; fo < OUT_FEAT; fo++) {
            as = fmaf(outv[fo], sAs[h * OUT_FEAT + fo], as);
            ad = fmaf(outv[fo], sAd[h * OUT_FEAT + fo], ad);
        }
        a_src[n * HEADS + h] = as;
        a_dst[n * HEADS + h] = ad;
    }
}

// ---------------------------------------------------------------------------
// K2: bucket accumulate v3.
//  - bin bucket's edges to per-node CSR in LDS (int atomics only)
//  - ex pass: per (edge,head) task computes exp(leakyrelu(a_src+a_dst)) once,
//    stores f16 into exl[edge*8+h]  (R9 lesson: 6 __shfl = 6 ds_bpermute per
//    edge were the latency chain; now ONE ds_read_b128 per edge fetches all
//    6 ex values, and den is 6 plain adds — zero shuffles in the hot loop)
//  - phase A: one wave per node, 4 edge slots x 16 features; per edge:
//    1 ushort gather (data_f16) + 1 ds_read_b128 + 6 cvt + 6 FMA + 6 add
//  - phase B: dense per-node W transform from LDS wsn, W via L1 (no MT
//    staging -> LDS 21.8 KB -> 7 blocks/CU)
// No fp atomics, no unroll (R9: VGPR 64 halved occupancy).
// ---------------------------------------------------------------------------
__global__ void bucket_accumulate(const int* __restrict__ gcursor,
                                  const unsigned int* __restrict__ spack,
                                  const float* __restrict__ data,
                                  const unsigned short* __restrict__ data_f16,
                                  const float* __restrict__ a_src,
                                  const float* __restrict__ a_dst,
                                  const float* __restrict__ W,
                                  const float* __restrict__ bias,
                                  float* __restrict__ out) {
    const int b = blockIdx.x;
    const int n0 = b * NPB;
    if (n0 >= N_NODES) return;
    const int nn = min(NPB, N_NODES - n0);

    __shared__ unsigned int olist[CAP];            // 2.3 KB
    __shared__ unsigned short exl[CAP * 8];        // 9.2 KB (f16, stride 8)
    __shared__ float wsn_l[NPB * 100];             // 10 KB, pad stride 100
    __shared__ int cnt[NPB];
    __shared__ int start[NPB + 1];
    __shared__ int cur[NPB];

    const int tid  = threadIdx.x;
    const int lane = tid & 63;
    const int slot = lane >> 4;       // 4 edge-slots per wave
    const int f    = lane & 15;       // feature/k index
    const int wv   = tid >> 6;        // wave id (0..3)

    int ecnt = gcursor[b] - b * CAP;
    if (ecnt > CAP) ecnt = CAP;       // statistically unreachable

    // ---- bin to per-node CSR in LDS ----
    for (int j = tid; j < NPB; j += 256) cnt[j] = 0;
    __syncthreads();
    for (int i = tid; i < ecnt; i += 256)
        atomicAdd(&cnt[spack[b * CAP + i] >> 17], 1);
    __syncthreads();
    if (tid == 0) {
        int r = 0;
        for (int j = 0; j < NPB; j++) { start[j] = r; r += cnt[j]; }
        start[NPB] = r;
    }
    __syncthreads();
    for (int j = tid; j < NPB; j += 256) cur[j] = start[j];
    __syncthreads();
    for (int i = tid; i < ecnt; i += 256) {
        unsigned int p = spack[b * CAP + i];
        int dl = (int)(p >> 17);
        int pos = atomicAdd(&cur[dl], 1);
        olist[pos] = p;                // keep dl packed for the ex pass
    }
    __syncthreads();

    // ---- ex pass: one task per (edge, head) ----
    for (int idx = tid; idx < ecnt * 8; idx += 256) {
        int i = idx >> 3, h = idx & 7;
        if (h < HEADS) {
            unsigned int p = olist[i];
            int s  = (int)(p & 0x1FFFFu);
            int dl = (int)(p >> 17);
            float e = a_src[s * HEADS + h] + a_dst[(n0 + dl) * HEADS + h];
            e = e > 0.f ? e : 0.2f * e;            // leaky relu
            exl[i * 8 + h] = __half_as_ushort(__float2half_rn(__expf(e)));
        }
    }
    __syncthreads();

    // ---- phase A: one wave per node ----
    for (int dl = wv; dl < nn; dl += 4) {
        const int s0 = start[dl];
        const int s1 = s0 + cnt[dl];

        float ws[HEADS], dn[HEADS];
#pragma unroll
        for (int h = 0; h < HEADS; h++) { ws[h] = 0.f; dn[h] = 0.f; }

        for (int pos = s0 + slot; pos < s1; pos += 4) {
            int s = (int)(olist[pos] & 0x1FFFFu);
            float dv = __half2float(__ushort_as_half(data_f16[(size_t)s * IN_FEAT + f]));
            uint4 e4 = *(const uint4*)(exl + pos * 8);   // 16B aligned, broadcast
            float ex0 = __half2float(__ushort_as_half((unsigned short)(e4.x & 0xFFFFu)));
            float ex1 = __half2float(__ushort_as_half((unsigned short)(e4.x >> 16)));
            float ex2 = __half2float(__ushort_as_half((unsigned short)(e4.y & 0xFFFFu)));
            float ex3 = __half2float(__ushort_as_half((unsigned short)(e4.y >> 16)));
            float ex4 = __half2float(__ushort_as_half((unsigned short)(e4.z & 0xFFFFu)));
            float ex5 = __half2float(__ushort_as_half((unsigned short)(e4.z >> 16)));
            ws[0] = fmaf(dv, ex0, ws[0]); dn[0] += ex0;
            ws[1] = fmaf(dv, ex1, ws[1]); dn[1] += ex1;
            ws[2] = fmaf(dv, ex2, ws[2]); dn[2] += ex2;
            ws[3] = fmaf(dv, ex3, ws[3]); dn[3] += ex3;
            ws[4] = fmaf(dv, ex4, ws[4]); dn[4] += ex4;
            ws[5] = fmaf(dv, ex5, ws[5]); dn[5] += ex5;
        }

        // reduce the 4 slots (den becomes identical on all lanes)
#pragma unroll
        for (int h = 0; h < HEADS; h++) {
            ws[h] += __shfl_xor(ws[h], 16, 64);
            ws[h] += __shfl_xor(ws[h], 32, 64);
            dn[h] += __shfl_xor(dn[h], 16, 64);
            dn[h] += __shfl_xor(dn[h], 32, 64);
        }

        if (slot == 0) {
            float cs = 0.f;
#pragma unroll
            for (int h = 0; h < HEADS; h++) {
                float wsn = ws[h] * __builtin_amdgcn_rcpf(dn[h] + 1e-16f);
                cs += wsn;
                wsn_l[dl * 100 + h * 16 + f] = wsn;
            }
            if (f < 2) {                      // fused coord output
                float c = cs * (0.2f / 6.f);
                float key = data[(size_t)(n0 + dl) * IN_FEAT + f];
                if (key == 1.0f)      c = 1.0f;
                else if (key == 0.0f) c = 0.0f;
                out[(n0 + dl) * 2 + f] = c;
            }
        }
    }
    __syncthreads();

    // ---- phase B: dense per-node transform; W via L1 (6 KB, hot) ----
    const float sc = 1.0507009873554805f;
    const float al = 1.6732632423543772f;
    for (int task = tid; task < nn * 16; task += 256) {
        int dl = task >> 4, fo = task & 15;
        float acc = 0.f;
#pragma unroll
        for (int h = 0; h < HEADS; h++) {
            const float* wr = wsn_l + dl * 100 + h * 16;
            const float* Wc = W + h * 16 + fo;
#pragma unroll
            for (int k = 0; k < IN_FEAT; k++)
                acc = fmaf(wr[k], Wc[k * HF], acc);
        }
        float v = acc * (1.f / 6.f) + bias[fo];
        v = v > 0.f ? sc * v : sc * al * (__expf(v) - 1.f);
        out[2 * N_NODES + (size_t)(n0 + dl) * OUT_FEAT + fo] = v;
    }
}

// ---------------------------------------------------------------------------
// Workspace layout (float offsets):
//   [0, 600000)            a_src    (N*6)
//   [600000, 1200000)      a_dst    (N*6)
//   [1200000, 1204096)     gcursor  (NB ints)
//   [1204096, 3563392)     spack    (NB*CAP uints = 9.4 MB)
//   [3563392, 4363392)     data_f16 (N*16 halves = 3.2 MB)
// Total ~17.5 MB.
// ---------------------------------------------------------------------------
extern "C" void kernel_launch(void* const* d_in, const int* in_sizes, int n_in,
                              void* d_out, int out_size, void* d_ws, size_t ws_size,
                              hipStream_t stream) {
    const float* data    = (const float*)d_in[0];
    const int*   eidx    = (const int*)d_in[1];      // int32 on device
    const float* W       = (const float*)d_in[2];
    const float* att_src = (const float*)d_in[3];
    const float* att_dst = (const float*)d_in[4];
    const float* bias    = (const float*)d_in[5];
    float*       out     = (float*)d_out;
    float*       ws      = (float*)d_ws;

    float*          a_src    = ws;
    float*          a_dst    = ws + 600000;
    int*            gcursor  = (int*)(ws + 1200000);
    unsigned int*   spack    = (unsigned int*)(ws + 1204096);
    unsigned short* data_f16 = (unsigned short*)(ws + 3563392);

    init_cursors<<<(NB + 255) / 256, 256, 0, stream>>>(gcursor);

    prep<<<NBLK_PART + NT_BLOCKS, 256, 0, stream>>>(
        eidx, eidx + N_EDGES, gcursor, spack,
        data, W, att_src, att_dst, a_src, a_dst, data_f16);

    bucket_accumulate<<<NB, 256, 0, stream>>>(
        gcursor, spack, data, data_f16, a_src, a_dst, W, bias, out);
}